// Round 4
// baseline (2233.417 us; speedup 1.0000x reference)
//
#include <hip/hip_runtime.h>

// Sinkhorn divergence, 512 independent 256-point problems, 24 annealing steps.
// Round 6: R1 structure (float4 LDS, uniform b128 broadcasts, 0 bank
// conflicts, 2 barriers/step) + packed-f32 (v_pk_fma/add/max_f32) inner
// math using ONLY named v2f variables — no ext-vector arrays (R3's arrays
// were demoted to scratch: 8 GB of HBM spill traffic, 3.3x regression).
// Each pass computes a PAIR of matrix elements per column sharing the
// column data, differing only in the row coefficient.
//
// Math (log2 domain, unchanged): online logsumexp with integer-quantized
// running max (ceilf) and ldexp rescale — exact identity.
//   softmin_i = 0.5||P_i||^2 - eps*ln2*( M_i + log2 sum_j 2^{arg_ij - M_i} )
//   arg_ij    = H2[j] + t_i*t_j*inv + p_i*(q_j*inv) ,  inv = log2e/eps

constexpr int   N       = 256;   // points per cloud
constexpr int   NPROB   = 512;   // B*S*NR
constexpr int   NRDIM   = 64;
constexpr float DT_F    = 0.001f;
constexpr float EPS_MIN = 1e-4f; // BLUR^P
constexpr int   NSTEPS  = 24;
constexpr float LOG2E   = 1.4426950408889634f;
constexpr float LN2     = 0.6931471805599453f;
constexpr int   NT      = 1024;  // threads per block
constexpr int   CPQ     = 64;    // columns per quarter

typedef float v2f __attribute__((ext_vector_type(2)));

static __device__ __forceinline__ v2f pkmax(v2f a, v2f b) {
    return __builtin_elementwise_max(a, b);
}

extern "C" __global__ void __launch_bounds__(NT, 8)
sinkhorn_div_kernel(const float* __restrict__ syn,
                    const float* __restrict__ obs,
                    float* __restrict__ divs)
{
    const int p   = blockIdx.x;          // ((b*S + s)*NR + r)
    const int r   = p & (NRDIM - 1);
    const int bs  = p >> 6;
    const int tid = threadIdx.x;
    const int row = tid & (N - 1);       // row index i (duplicated x4)
    const int q   = tid >> 8;            // column quarter 0..3

    __shared__ float4 ya[N];             // (Hxy, Hyy, y_j*inv, 0)
    __shared__ float4 xa[N];             // (Hyx, Hxx, x_j*inv, 0)
    __shared__ float4 msh[NT];           // per-thread (m_xy, m_yy, s_xy, s_yy)
    __shared__ float4 ssh[NT];           // per-thread (m_yx, m_xx, s_yx, s_xx)
    __shared__ float  redA[64];

    const size_t base = (size_t)bs * N * NRDIM + r;
    const float xi = obs[base + (size_t)row * NRDIM];   // x cloud = obs
    const float yi = syn[base + (size_t)row * NRDIM];   // y cloud = syn

    // ---- block reductions: diameter (max/min) + all-zero mask sums ----
    float hi = fmaxf(xi, yi), lo = fminf(xi, yi);
    float ax = fabsf(xi),     ay = fabsf(yi);
    #pragma unroll
    for (int off = 32; off > 0; off >>= 1) {
        hi  = fmaxf(hi, __shfl_down(hi, off, 64));
        lo  = fminf(lo, __shfl_down(lo, off, 64));
        ax += __shfl_down(ax, off, 64);
        ay += __shfl_down(ay, off, 64);
    }
    const int wave = tid >> 6;           // 0..15
    if ((tid & 63) == 0) {
        redA[wave * 4 + 0] = hi;  redA[wave * 4 + 1] = lo;
        redA[wave * 4 + 2] = ax;  redA[wave * 4 + 3] = ay;
    }
    __syncthreads();
    float vmax = -3.4e38f, vmin = 3.4e38f, sax = 0.0f, say = 0.0f;
    #pragma unroll
    for (int w = 0; w < 16; ++w) {
        vmax = fmaxf(vmax, redA[w * 4 + 0]);
        vmin = fminf(vmin, redA[w * 4 + 1]);
        sax += redA[w * 4 + 2];
        say += redA[w * 4 + 3];
    }

    const float tspread  = 255.0f * DT_F;
    const float diameter = fmaxf(tspread, vmax - vmin);
    float eps_raw = diameter * diameter;              // eps0 = diameter^2

    const float ti    = (float)row * DT_F;
    const float selfx = 0.5f * (ti * ti + xi * xi);
    const float selfy = 0.5f * (ti * ti + yi * yi);

    float f = 0.0f, g = 0.0f, px = 0.0f, py = 0.0f;

    const int j0 = q * CPQ;

    for (int step = 0; step < NSTEPS; ++step) {
        const float eps = fmaxf(eps_raw, EPS_MIN);
        const float inv = LOG2E / eps;

        // ---- prologue: quarter 0 provides column j = row of all arrays ----
        if (q == 0) {
            const float la2 = -8.0f;   // log2(1/256)
            const float Hxy = fmaf(g  - selfy, inv, la2);
            const float Hyy = fmaf(py - selfy, inv, la2);
            const float Hyx = fmaf(f  - selfx, inv, la2);
            const float Hxx = fmaf(px - selfx, inv, la2);
            ya[row] = make_float4(Hxy, Hyy, yi * inv, 0.0f);
            xa[row] = make_float4(Hyx, Hxx, xi * inv, 0.0f);
        }
        __syncthreads();   // S1

        const float a  = ti * DT_F * inv;     // t-term increment per j
        const float a8 = 8.0f * a;

#define EXP2(x) __builtin_amdgcn_exp2f(x)

// One column: load float4, build packed arg pair u##K.
#define COLPAIR(ARR, CP, K) \
            const float4 Q##K = ARR[jb + K]; \
            const float  r##K = fmaf((float)K, a, rr0); \
            const v2f    u##K = __builtin_elementwise_fma( \
                CP, (v2f){Q##K.z, Q##K.z}, \
                (v2f){Q##K.x, Q##K.y} + (v2f){r##K, r##K});

#define CHUNK_BODY(ARR, CP) \
            COLPAIR(ARR, CP, 0) COLPAIR(ARR, CP, 1) \
            COLPAIR(ARR, CP, 2) COLPAIR(ARR, CP, 3) \
            COLPAIR(ARR, CP, 4) COLPAIR(ARR, CP, 5) \
            COLPAIR(ARR, CP, 6) COLPAIR(ARR, CP, 7) \
            const v2f mc = pkmax(pkmax(pkmax(u0, u1), pkmax(u2, u3)), \
                                 pkmax(pkmax(u4, u5), pkmax(u6, u7))); \
            const v2f Mv = pkmax(mprev, (v2f){ceilf(mc.x), ceilf(mc.y)}); \
            const v2f w0 = u0 - Mv;  const v2f w1 = u1 - Mv; \
            const v2f w2 = u2 - Mv;  const v2f w3 = u3 - Mv; \
            const v2f w4 = u4 - Mv;  const v2f w5 = u5 - Mv; \
            const v2f w6 = u6 - Mv;  const v2f w7 = u7 - Mv; \
            const float tx = ((EXP2(w0.x) + EXP2(w1.x)) + (EXP2(w2.x) + EXP2(w3.x))) \
                           + ((EXP2(w4.x) + EXP2(w5.x)) + (EXP2(w6.x) + EXP2(w7.x))); \
            const float ty = ((EXP2(w0.y) + EXP2(w1.y)) + (EXP2(w2.y) + EXP2(w3.y))) \
                           + ((EXP2(w4.y) + EXP2(w5.y)) + (EXP2(w6.y) + EXP2(w7.y))); \
            sA = ldexpf(sA, (int)(mprev.x - Mv.x)) + tx; \
            sB = ldexpf(sB, (int)(mprev.y - Mv.y)) + ty; \
            mprev = Mv;

        // ========== pass A: pair (xy, yy) over ya ==========
        {
            v2f   mprev = {-1e9f, -1e9f};
            float sA = 0.0f, sB = 0.0f;
            const v2f cA = {xi, yi};
            float rr0 = a * (float)j0;
            for (int cc = 0; cc < CPQ; cc += 8) {
                const int jb = j0 + cc;
                CHUNK_BODY(ya, cA)
                rr0 += a8;
            }
            msh[tid] = make_float4(mprev.x, mprev.y, sA, sB);
        }

        // ========== pass B: pair (yx, xx) over xa ==========
        {
            v2f   mprev = {-1e9f, -1e9f};
            float sA = 0.0f, sB = 0.0f;
            const v2f cB = {yi, xi};
            float rr0 = a * (float)j0;
            for (int cc = 0; cc < CPQ; cc += 8) {
                const int jb = j0 + cc;
                CHUNK_BODY(xa, cB)
                rr0 += a8;
            }
            ssh[tid] = make_float4(mprev.x, mprev.y, sA, sB);
        }
#undef CHUNK_BODY
#undef COLPAIR
        __syncthreads();   // S2

        // ---- combine (m,s) across the 4 quarters (identical in all) ------
        const float4 A0 = msh[row];
        const float4 A1 = msh[row + 256];
        const float4 A2 = msh[row + 512];
        const float4 A3 = msh[row + 768];
        const float4 B0 = ssh[row];
        const float4 B1 = ssh[row + 256];
        const float4 B2 = ssh[row + 512];
        const float4 B3 = ssh[row + 768];

        const float Mxy = fmaxf(fmaxf(A0.x, A1.x), fmaxf(A2.x, A3.x));
        const float Myy = fmaxf(fmaxf(A0.y, A1.y), fmaxf(A2.y, A3.y));
        const float Myx = fmaxf(fmaxf(B0.x, B1.x), fmaxf(B2.x, B3.x));
        const float Mxx = fmaxf(fmaxf(B0.y, B1.y), fmaxf(B2.y, B3.y));

        const float Sxy = (ldexpf(A0.z, (int)(A0.x - Mxy)) + ldexpf(A1.z, (int)(A1.x - Mxy)))
                        + (ldexpf(A2.z, (int)(A2.x - Mxy)) + ldexpf(A3.z, (int)(A3.x - Mxy)));
        const float Syy = (ldexpf(A0.w, (int)(A0.y - Myy)) + ldexpf(A1.w, (int)(A1.y - Myy)))
                        + (ldexpf(A2.w, (int)(A2.y - Myy)) + ldexpf(A3.w, (int)(A3.y - Myy)));
        const float Syx = (ldexpf(B0.z, (int)(B0.x - Myx)) + ldexpf(B1.z, (int)(B1.x - Myx)))
                        + (ldexpf(B2.z, (int)(B2.x - Myx)) + ldexpf(B3.z, (int)(B3.x - Myx)));
        const float Sxx = (ldexpf(B0.w, (int)(B0.y - Mxx)) + ldexpf(B1.w, (int)(B1.y - Mxx)))
                        + (ldexpf(B2.w, (int)(B2.y - Mxx)) + ldexpf(B3.w, (int)(B3.y - Mxx)));

        // ---- epilogue: every quarter computes identical new potentials ----
        const float el2 = eps * LN2;
        const float fn  = selfx - el2 * (Mxy + __builtin_amdgcn_logf(Sxy));
        const float gn  = selfy - el2 * (Myx + __builtin_amdgcn_logf(Syx));
        const float pxn = 0.5f * (px + (selfx - el2 * (Mxx + __builtin_amdgcn_logf(Sxx))));
        const float pyn = 0.5f * (py + (selfy - el2 * (Myy + __builtin_amdgcn_logf(Syy))));
        f = fn; g = gn; px = pxn; py = pyn;

        eps_raw *= 0.25f;
        // no barrier here: S1 of the next step separates the prologue write
        // (after this point) from this step's pass reads (before S2).
    }

    // ---- divergence: (1/n) * sum_i [(f-px)+(g-py)], rows duplicated x4 ----
    float contrib = (f - px) + (g - py);
    #pragma unroll
    for (int off = 32; off > 0; off >>= 1)
        contrib += __shfl_down(contrib, off, 64);
    __syncthreads();                      // redA reuse
    if ((tid & 63) == 0) redA[wave] = contrib;
    __syncthreads();
    if (tid == 0) {
        float total = 0.0f;
        #pragma unroll
        for (int w = 0; w < 16; ++w) total += redA[w];
        total *= (1.0f / (float)(4 * N));             // x4 duplication
        const bool masked_out = (sax == 0.0f) && (say == 0.0f);
        divs[p] = masked_out ? 0.0f : total;
    }
}

extern "C" __global__ void __launch_bounds__(256)
reduce_out_kernel(const float* __restrict__ divs, float* __restrict__ out)
{
    const int b   = blockIdx.x;
    const int tid = threadIdx.x;
    __shared__ float red[4];
    float v = divs[b * 256 + tid];        // 256 = S*NR problems per batch
    #pragma unroll
    for (int off = 32; off > 0; off >>= 1)
        v += __shfl_down(v, off, 64);
    if ((tid & 63) == 0) red[tid >> 6] = v;
    __syncthreads();
    if (tid == 0) out[b] = red[0] + red[1] + red[2] + red[3];
}

extern "C" void kernel_launch(void* const* d_in, const int* in_sizes, int n_in,
                              void* d_out, int out_size, void* d_ws, size_t ws_size,
                              hipStream_t stream) {
    const float* syn = (const float*)d_in[0];   // syn_data
    const float* obs = (const float*)d_in[1];   // obs_data
    float* divs = (float*)d_ws;                 // 512 floats scratch

    sinkhorn_div_kernel<<<NPROB, NT, 0, stream>>>(syn, obs, divs);
    reduce_out_kernel<<<2, 256, 0, stream>>>(divs, (float*)d_out);
}

// Round 5
// 599.274 us; speedup vs baseline: 3.7269x; 3.7269x over previous
//
#include <hip/hip_runtime.h>

// Sinkhorn divergence, 512 independent 256-point problems, 24 annealing steps.
// Round 7: R1 scalar structure (float4 LDS, wave-uniform broadcast b128
// reads, 0 bank conflicts, 2 barriers/step) with three scalar-only changes:
//  1. 8 upfront named float4 loads per chunk -> ds_reads issue back-to-back,
//     one lgkm wait per chunk (R1's VGPR=32 forced load-use stalls).
//  2. .w field carries t_j*inv -> arg = fmaf(ti, Q.w, fmaf(coef, Q.z, Q.x));
//     kills the rr/rk t-term bookkeeping.
//  3. Combine+epilogue only in quarter 0 (prologue is q0-only anyway);
//     q1..q3 skip to the next barrier. Final sum from q0, scale 1/N.
// NO ext_vector types: R3/R4 proved hipcc demotes v2f temporaries to
// scratch here (8 GB HBM spill traffic, 3.3x regression).
//
// Math (log2 domain, unchanged): online logsumexp, integer-quantized
// running max (ceilf), ldexp rescale — exact identity.
//   softmin_i = 0.5||P_i||^2 - eps*ln2*( M_i + log2 sum_j 2^{arg_ij - M_i} )
//   arg_ij    = H2[j] + t_i*(t_j*inv) + p_i*(q_j*inv) ,  inv = log2e/eps

constexpr int   N       = 256;   // points per cloud
constexpr int   NPROB   = 512;   // B*S*NR
constexpr int   NRDIM   = 64;
constexpr float DT_F    = 0.001f;
constexpr float EPS_MIN = 1e-4f; // BLUR^P
constexpr int   NSTEPS  = 24;
constexpr float LOG2E   = 1.4426950408889634f;
constexpr float LN2     = 0.6931471805599453f;
constexpr int   NT      = 1024;  // threads per block
constexpr int   CPQ     = 64;    // columns per quarter

extern "C" __global__ void __launch_bounds__(NT, 8)
sinkhorn_div_kernel(const float* __restrict__ syn,
                    const float* __restrict__ obs,
                    float* __restrict__ divs)
{
    const int p   = blockIdx.x;          // ((b*S + s)*NR + r)
    const int r   = p & (NRDIM - 1);
    const int bs  = p >> 6;
    const int tid = threadIdx.x;
    const int row = tid & (N - 1);       // row index i (duplicated x4)
    const int q   = tid >> 8;            // column quarter 0..3

    __shared__ float4 ya[N];             // (Hxy, Hyy, y_j*inv, t_j*inv)
    __shared__ float4 xa[N];             // (Hyx, Hxx, x_j*inv, t_j*inv)
    __shared__ float4 msh[NT];           // per-thread (m_xy, m_yy, s_xy, s_yy)
    __shared__ float4 ssh[NT];           // per-thread (m_yx, m_xx, s_yx, s_xx)
    __shared__ float  redA[64];

    const size_t base = (size_t)bs * N * NRDIM + r;
    const float xi = obs[base + (size_t)row * NRDIM];   // x cloud = obs
    const float yi = syn[base + (size_t)row * NRDIM];   // y cloud = syn

    // ---- block reductions: diameter (max/min) + all-zero mask sums ----
    float hi = fmaxf(xi, yi), lo = fminf(xi, yi);
    float ax = fabsf(xi),     ay = fabsf(yi);
    #pragma unroll
    for (int off = 32; off > 0; off >>= 1) {
        hi  = fmaxf(hi, __shfl_down(hi, off, 64));
        lo  = fminf(lo, __shfl_down(lo, off, 64));
        ax += __shfl_down(ax, off, 64);
        ay += __shfl_down(ay, off, 64);
    }
    const int wave = tid >> 6;           // 0..15
    if ((tid & 63) == 0) {
        redA[wave * 4 + 0] = hi;  redA[wave * 4 + 1] = lo;
        redA[wave * 4 + 2] = ax;  redA[wave * 4 + 3] = ay;
    }
    __syncthreads();
    float vmax = -3.4e38f, vmin = 3.4e38f, sax = 0.0f, say = 0.0f;
    #pragma unroll
    for (int w = 0; w < 16; ++w) {
        vmax = fmaxf(vmax, redA[w * 4 + 0]);
        vmin = fminf(vmin, redA[w * 4 + 1]);
        sax += redA[w * 4 + 2];
        say += redA[w * 4 + 3];
    }

    const float tspread  = 255.0f * DT_F;
    const float diameter = fmaxf(tspread, vmax - vmin);
    float eps_raw = diameter * diameter;              // eps0 = diameter^2

    const float ti    = (float)row * DT_F;
    const float selfx = 0.5f * (ti * ti + xi * xi);
    const float selfy = 0.5f * (ti * ti + yi * yi);

    float f = 0.0f, g = 0.0f, px = 0.0f, py = 0.0f;

    const int j0 = q * CPQ;

#define EXP2(x) __builtin_amdgcn_exp2f(x)

// One chunk of 8 columns over array ARR; computes 2 matrices with row
// coefficients C1 (into m0/s0) and C2 (into m1/s1). All scalars, named.
#define CHUNK(ARR) \
        { \
            const float4 Q0 = ARR[jb + 0]; \
            const float4 Q1 = ARR[jb + 1]; \
            const float4 Q2 = ARR[jb + 2]; \
            const float4 Q3 = ARR[jb + 3]; \
            const float4 Q4 = ARR[jb + 4]; \
            const float4 Q5 = ARR[jb + 5]; \
            const float4 Q6 = ARR[jb + 6]; \
            const float4 Q7 = ARR[jb + 7]; \
            const float b0 = fmaf(ti, Q0.w, fmaf(C1, Q0.z, Q0.x)); \
            const float c0 = fmaf(ti, Q0.w, fmaf(C2, Q0.z, Q0.y)); \
            const float b1 = fmaf(ti, Q1.w, fmaf(C1, Q1.z, Q1.x)); \
            const float c1 = fmaf(ti, Q1.w, fmaf(C2, Q1.z, Q1.y)); \
            const float b2 = fmaf(ti, Q2.w, fmaf(C1, Q2.z, Q2.x)); \
            const float c2 = fmaf(ti, Q2.w, fmaf(C2, Q2.z, Q2.y)); \
            const float b3 = fmaf(ti, Q3.w, fmaf(C1, Q3.z, Q3.x)); \
            const float c3 = fmaf(ti, Q3.w, fmaf(C2, Q3.z, Q3.y)); \
            const float b4 = fmaf(ti, Q4.w, fmaf(C1, Q4.z, Q4.x)); \
            const float c4 = fmaf(ti, Q4.w, fmaf(C2, Q4.z, Q4.y)); \
            const float b5 = fmaf(ti, Q5.w, fmaf(C1, Q5.z, Q5.x)); \
            const float c5 = fmaf(ti, Q5.w, fmaf(C2, Q5.z, Q5.y)); \
            const float b6 = fmaf(ti, Q6.w, fmaf(C1, Q6.z, Q6.x)); \
            const float c6 = fmaf(ti, Q6.w, fmaf(C2, Q6.z, Q6.y)); \
            const float b7 = fmaf(ti, Q7.w, fmaf(C1, Q7.z, Q7.x)); \
            const float c7 = fmaf(ti, Q7.w, fmaf(C2, Q7.z, Q7.y)); \
            /* 9-leaf max trees (m0/m1 are integer-valued, ceil-safe) */ \
            const float bt0 = fmaxf(fmaxf(b0, b1), b2); \
            const float bt1 = fmaxf(fmaxf(b3, b4), b5); \
            const float bt2 = fmaxf(fmaxf(b6, b7), m0); \
            const float M0  = ceilf(fmaxf(fmaxf(bt0, bt1), bt2)); \
            const float ct0 = fmaxf(fmaxf(c0, c1), c2); \
            const float ct1 = fmaxf(fmaxf(c3, c4), c5); \
            const float ct2 = fmaxf(fmaxf(c6, c7), m1); \
            const float M1  = ceilf(fmaxf(fmaxf(ct0, ct1), ct2)); \
            const float t0 = \
                ((EXP2(b0 - M0) + EXP2(b1 - M0)) + (EXP2(b2 - M0) + EXP2(b3 - M0))) + \
                ((EXP2(b4 - M0) + EXP2(b5 - M0)) + (EXP2(b6 - M0) + EXP2(b7 - M0))); \
            const float t1 = \
                ((EXP2(c0 - M1) + EXP2(c1 - M1)) + (EXP2(c2 - M1) + EXP2(c3 - M1))) + \
                ((EXP2(c4 - M1) + EXP2(c5 - M1)) + (EXP2(c6 - M1) + EXP2(c7 - M1))); \
            s0 = ldexpf(s0, (int)(m0 - M0)) + t0;  m0 = M0; \
            s1 = ldexpf(s1, (int)(m1 - M1)) + t1;  m1 = M1; \
        }

    for (int step = 0; step < NSTEPS; ++step) {
        const float eps = fmaxf(eps_raw, EPS_MIN);
        const float inv = LOG2E / eps;

        // ---- prologue: quarter 0 provides column j = row of all arrays ----
        if (q == 0) {
            const float la2 = -8.0f;   // log2(1/256)
            const float Hxy = fmaf(g  - selfy, inv, la2);
            const float Hyy = fmaf(py - selfy, inv, la2);
            const float Hyx = fmaf(f  - selfx, inv, la2);
            const float Hxx = fmaf(px - selfx, inv, la2);
            const float tji = ti * inv;          // t_j * inv for column j=row
            ya[row] = make_float4(Hxy, Hyy, yi * inv, tji);
            xa[row] = make_float4(Hyx, Hxx, xi * inv, tji);
        }
        __syncthreads();   // S1

        // ========== pass A: pair (xy via xi, yy via yi) over ya ==========
        {
            float m0 = -1e9f, m1 = -1e9f, s0 = 0.0f, s1 = 0.0f;
            const float C1 = xi, C2 = yi;
            #pragma unroll
            for (int cc = 0; cc < CPQ; cc += 8) {
                const int jb = j0 + cc;
                CHUNK(ya)
            }
            msh[tid] = make_float4(m0, m1, s0, s1);
        }

        // ========== pass B: pair (yx via yi, xx via xi) over xa ==========
        {
            float m0 = -1e9f, m1 = -1e9f, s0 = 0.0f, s1 = 0.0f;
            const float C1 = yi, C2 = xi;
            #pragma unroll
            for (int cc = 0; cc < CPQ; cc += 8) {
                const int jb = j0 + cc;
                CHUNK(xa)
            }
            ssh[tid] = make_float4(m0, m1, s0, s1);
        }
        __syncthreads();   // S2

        // ---- combine + epilogue: quarter 0 only (sole prologue producer) --
        if (q == 0) {
            const float4 A0 = msh[row];
            const float4 A1 = msh[row + 256];
            const float4 A2 = msh[row + 512];
            const float4 A3 = msh[row + 768];
            const float4 B0 = ssh[row];
            const float4 B1 = ssh[row + 256];
            const float4 B2 = ssh[row + 512];
            const float4 B3 = ssh[row + 768];

            const float Mxy = fmaxf(fmaxf(A0.x, A1.x), fmaxf(A2.x, A3.x));
            const float Myy = fmaxf(fmaxf(A0.y, A1.y), fmaxf(A2.y, A3.y));
            const float Myx = fmaxf(fmaxf(B0.x, B1.x), fmaxf(B2.x, B3.x));
            const float Mxx = fmaxf(fmaxf(B0.y, B1.y), fmaxf(B2.y, B3.y));

            const float Sxy = (ldexpf(A0.z, (int)(A0.x - Mxy)) + ldexpf(A1.z, (int)(A1.x - Mxy)))
                            + (ldexpf(A2.z, (int)(A2.x - Mxy)) + ldexpf(A3.z, (int)(A3.x - Mxy)));
            const float Syy = (ldexpf(A0.w, (int)(A0.y - Myy)) + ldexpf(A1.w, (int)(A1.y - Myy)))
                            + (ldexpf(A2.w, (int)(A2.y - Myy)) + ldexpf(A3.w, (int)(A3.y - Myy)));
            const float Syx = (ldexpf(B0.z, (int)(B0.x - Myx)) + ldexpf(B1.z, (int)(B1.x - Myx)))
                            + (ldexpf(B2.z, (int)(B2.x - Myx)) + ldexpf(B3.z, (int)(B3.x - Myx)));
            const float Sxx = (ldexpf(B0.w, (int)(B0.y - Mxx)) + ldexpf(B1.w, (int)(B1.y - Mxx)))
                            + (ldexpf(B2.w, (int)(B2.y - Mxx)) + ldexpf(B3.w, (int)(B3.y - Mxx)));

            const float el2 = eps * LN2;
            const float fn  = selfx - el2 * (Mxy + __builtin_amdgcn_logf(Sxy));
            const float gn  = selfy - el2 * (Myx + __builtin_amdgcn_logf(Syx));
            const float pxn = 0.5f * (px + (selfx - el2 * (Mxx + __builtin_amdgcn_logf(Sxx))));
            const float pyn = 0.5f * (py + (selfy - el2 * (Myy + __builtin_amdgcn_logf(Syy))));
            f = fn; g = gn; px = pxn; py = pyn;
        }

        eps_raw *= 0.25f;
        // no barrier here: next step's S1 separates the q0 prologue write
        // (post-combine) from this step's pass reads, and this step's
        // combine reads (pre-S1) from next step's msh/ssh writes (post-S1).
    }
#undef CHUNK
#undef EXP2

    // ---- divergence: (1/n) * sum_i [(f-px)+(g-py)] — quarter 0 only ----
    float contrib = (q == 0) ? ((f - px) + (g - py)) : 0.0f;
    #pragma unroll
    for (int off = 32; off > 0; off >>= 1)
        contrib += __shfl_down(contrib, off, 64);
    __syncthreads();                      // redA reuse
    if ((tid & 63) == 0) redA[wave] = contrib;
    __syncthreads();
    if (tid == 0) {
        float total = 0.0f;
        #pragma unroll
        for (int w = 0; w < 16; ++w) total += redA[w];
        total *= (1.0f / (float)N);
        const bool masked_out = (sax == 0.0f) && (say == 0.0f);
        divs[p] = masked_out ? 0.0f : total;
    }
}

extern "C" __global__ void __launch_bounds__(256)
reduce_out_kernel(const float* __restrict__ divs, float* __restrict__ out)
{
    const int b   = blockIdx.x;
    const int tid = threadIdx.x;
    __shared__ float red[4];
    float v = divs[b * 256 + tid];        // 256 = S*NR problems per batch
    #pragma unroll
    for (int off = 32; off > 0; off >>= 1)
        v += __shfl_down(v, off, 64);
    if ((tid & 63) == 0) red[tid >> 6] = v;
    __syncthreads();
    if (tid == 0) out[b] = red[0] + red[1] + red[2] + red[3];
}

extern "C" void kernel_launch(void* const* d_in, const int* in_sizes, int n_in,
                              void* d_out, int out_size, void* d_ws, size_t ws_size,
                              hipStream_t stream) {
    const float* syn = (const float*)d_in[0];   // syn_data
    const float* obs = (const float*)d_in[1];   // obs_data
    float* divs = (float*)d_ws;                 // 512 floats scratch

    sinkhorn_div_kernel<<<NPROB, NT, 0, stream>>>(syn, obs, divs);
    reduce_out_kernel<<<2, 256, 0, stream>>>(divs, (float*)d_out);
}